// Round 10
// baseline (132.649 us; speedup 1.0000x reference)
//
#include <hip/hip_runtime.h>
#include <math.h>

#pragma clang fp contract(off)

typedef unsigned long long u64;
typedef unsigned int u32;
typedef float f4 __attribute__((ext_vector_type(4)));
typedef unsigned long long u64x2 __attribute__((ext_vector_type(2)));

#define BB 8
#define CC_TOT 1203
#define NANC 8400
#define NSEL 1000
#define NCAND 1024
#define NT 1024
#define NBATCH 128
#define NCHUNK_MAX 16

// order-preserving transform: float -> u32 with unsigned order == float order
__device__ __forceinline__ u32 okey32(float v) {
  u32 b = __float_as_uint(v);
  return (b & 0x80000000u) ? ~b : (b | 0x80000000u);
}

__device__ __forceinline__ float unokey32(u32 ok) {
  u32 fb = (ok & 0x80000000u) ? (ok & 0x7FFFFFFFu) : ~ok;
  return __uint_as_float(fb);
}

// ---------------- kernel 1 (unchanged — ~94% of achievable HBM BW): per-(tile,chunk,image) block ----
__global__ __launch_bounds__(256) void kmax(const float* __restrict__ cls0,
                                            const float* __restrict__ cls1,
                                            const float* __restrict__ cls2,
                                            u64* __restrict__ part,
                                            int chunkSz, int nchunk) {
  int bx = blockIdx.x;
  int per = nchunk * BB;
  int tg = bx / per;
  int rem = bx - tg * per;
  int chunk = rem >> 3;
  int b = rem & 7;
  const float* cls; int hw4, aoff, col0;
  if (tg < 7)      { cls = cls0; hw4 = 1600; aoff = 0;    col0 = tg << 8; }
  else if (tg < 9) { cls = cls1; hw4 = 400;  aoff = 6400; col0 = (tg - 7) << 8; }
  else             { cls = cls2; hw4 = 100;  aoff = 8000; col0 = 0; }
  int col = col0 + (int)threadIdx.x;
  if (col >= hw4) return;
  int c0 = chunk * chunkSz;
  int c1 = c0 + chunkSz; if (c1 > CC_TOT) c1 = CC_TOT;

  const f4* base = (const f4*)cls + (size_t)b * CC_TOT * hw4 + col;
  f4 m = (f4){-3.4e38f, -3.4e38f, -3.4e38f, -3.4e38f};
  int ix0 = c0, ix1 = c0, ix2 = c0, ix3 = c0;

#define UPD(v, c)                                   \
  do {                                              \
    if ((v)[0] > m[0]) { m[0] = (v)[0]; ix0 = (c); } \
    if ((v)[1] > m[1]) { m[1] = (v)[1]; ix1 = (c); } \
    if ((v)[2] > m[2]) { m[2] = (v)[2]; ix2 = (c); } \
    if ((v)[3] > m[3]) { m[3] = (v)[3]; ix3 = (c); } \
  } while (0)

  int c = c0;
  for (; c + 8 <= c1; c += 8) {
    const f4* p = base + (size_t)c * hw4;
    f4 v0 = p[0];
    f4 v1 = p[(size_t)1 * hw4];
    f4 v2 = p[(size_t)2 * hw4];
    f4 v3 = p[(size_t)3 * hw4];
    f4 v4 = p[(size_t)4 * hw4];
    f4 v5 = p[(size_t)5 * hw4];
    f4 v6 = p[(size_t)6 * hw4];
    f4 v7 = p[(size_t)7 * hw4];
    UPD(v0, c + 0); UPD(v1, c + 1); UPD(v2, c + 2); UPD(v3, c + 3);
    UPD(v4, c + 4); UPD(v5, c + 5); UPD(v6, c + 6); UPD(v7, c + 7);
  }
  for (; c < c1; ++c) {
    f4 v = base[(size_t)c * hw4];
    UPD(v, c);
  }
#undef UPD

  u64* dst = part + ((size_t)chunk * BB + b) * NANC + aoff + (size_t)col * 4;
  u64x2 s01 = { ((u64)okey32(m[0]) << 32) | (u64)(u32)~(u32)ix0,
                ((u64)okey32(m[1]) << 32) | (u64)(u32)~(u32)ix1 };
  u64x2 s23 = { ((u64)okey32(m[2]) << 32) | (u64)(u32)~(u32)ix2,
                ((u64)okey32(m[3]) << 32) | (u64)(u32)~(u32)ix3 };
  *((u64x2*)dst)     = s01;
  *((u64x2*)dst + 1) = s23;
}

// ---------------- kernel 2: fused reduce + top-128 select + matrix NMS ----------------
struct DecodeArrays {
  float xo1[NCAND], yo1[NCAND], xo2[NCAND], yo2[NCAND], ar[NCAND];
  float rx1[NCAND], ry1[NCAND], rx2[NCAND], ry2[NCAND], sc[NCAND];
  int lab[NCAND], val[NCAND];
};

// reduce partial planes -> final sort key for anchor pair; key:
// (okey(logit)<<32) | ((65535-anchor)<<16) | label   (bits 16..63 unique)
__device__ __forceinline__ u64x2 reduce_pair(const u64x2* psrc, size_t PL2, int nchunk, int i) {
  u64x2 m = psrc[i];
  for (int ch = 1; ch < nchunk; ++ch) {
    u64x2 v = psrc[(size_t)ch * PL2 + i];
    if (v[0] > m[0]) m[0] = v[0];
    if (v[1] > m[1]) m[1] = v[1];
  }
  u32 i0 = (u32)(2 * i), i1 = (u32)(2 * i + 1);
  u64x2 r;
  r[0] = (m[0] & 0xFFFFFFFF00000000ull) | ((u64)(0xFFFFu - i0) << 16) | (u64)(~(u32)m[0] & 0xFFFFu);
  r[1] = (m[1] & 0xFFFFFFFF00000000ull) | ((u64)(0xFFFFu - i1) << 16) | (u64)(~(u32)m[1] & 0xFFFFu);
  return r;
}

// ballot-clustered histogram add, 12-bit digit (all lanes carry a valid digit)
__device__ __forceinline__ void hist_add12(u32* hist, u32 digit, int lane) {
  u64 peers = ~0ull;
  for (int bit = 0; bit < 12; ++bit) {
    u64 bal = __ballot((digit >> bit) & 1u);
    peers &= ((digit >> bit) & 1u) ? bal : ~bal;
  }
  int leader = __ffsll((unsigned long long)peers) - 1;
  if (lane == leader)
    atomicAdd(&hist[digit], (u32)__popcll((unsigned long long)peers));
}

// 13-bit variant with sentinel support (digit==4096 contributes nothing)
__device__ __forceinline__ void hist_add_clustered(u32* hist, u32 digit, int lane) {
  u64 peers = ~0ull;
  for (int bit = 0; bit < 13; ++bit) {
    u64 bal = __ballot((digit >> bit) & 1u);
    peers &= ((digit >> bit) & 1u) ? bal : ~bal;
  }
  int leader = __ffsll((unsigned long long)peers) - 1;
  if (digit < 4096u && lane == leader)
    atomicAdd(&hist[digit], (u32)__popcll((unsigned long long)peers));
}

// suffix-scan over 4096 bins + pick crossing digit; also reports crossing-bin count.
// ALL threads must call (has barriers).
__device__ __forceinline__ void suffix_pick(u32* hist, u32* waveTot, u32* waveSufExcl,
                                            u64* prefixSh, u32* rankSh, u32* binCntSh,
                                            u64 prefix, u32 rank, int shift,
                                            int tid, int lane, int wv) {
  u32 l0 = hist[4 * tid], l1 = hist[4 * tid + 1], l2 = hist[4 * tid + 2], l3 = hist[4 * tid + 3];
  u32 psum = l0 + l1 + l2 + l3;
  u32 x = psum;
  for (int s = 1; s < 64; s <<= 1) { u32 v = __shfl_down(x, s); if (lane + s < 64) x += v; }
  if (lane == 0) waveTot[wv] = x;
  __syncthreads();
  if (tid < 16) {
    u32 y = waveTot[tid]; u32 z = y;
    for (int s = 1; s < 16; s <<= 1) { u32 v = __shfl_down(z, s); if (tid + s < 16) z += v; }
    waveSufExcl[tid] = z - y;
  }
  __syncthreads();
  u32 S = x + waveSufExcl[wv];
  u32 G3 = S - psum; u32 G2 = G3 + l3; u32 G1 = G2 + l2; u32 G0 = G1 + l1;
  u32 r = rank;
  if      (G3 < r && G3 + l3 >= r) { *prefixSh = prefix | ((u64)(4u * tid + 3) << shift); *rankSh = r - G3; *binCntSh = l3; }
  else if (G2 < r && G2 + l2 >= r) { *prefixSh = prefix | ((u64)(4u * tid + 2) << shift); *rankSh = r - G2; *binCntSh = l2; }
  else if (G1 < r && G1 + l1 >= r) { *prefixSh = prefix | ((u64)(4u * tid + 1) << shift); *rankSh = r - G1; *binCntSh = l1; }
  else if (G0 < r && G0 + l0 >= r) { *prefixSh = prefix | ((u64)(4u * tid + 0) << shift); *rankSh = r - G0; *binCntSh = l0; }
}

// full exact rank-'target' select over keys[0..n) (fallback / pathological path)
__device__ __forceinline__ u64 radix_select(const u64* keys, int n, u32 target,
                                            u32* hist, u32* waveTot, u32* waveSufExcl,
                                            u64* prefixSh, u32* rankSh, u32* binCntSh,
                                            int tid, int lane, int wv) {
  u64 prefix = 0; u32 rank = target;
  for (int pass = 3; pass >= 0; --pass) {
    int shift = 16 + pass * 12;
    for (int i = tid; i < 4096; i += NT) hist[i] = 0;
    __syncthreads();
    u64 hiMask = (pass == 3) ? 0ull : ((~0ull) << (shift + 12));
    if (pass == 3) {
      for (int i = tid; i < n; i += NT) {
        u64 k = keys[i];
        hist_add_clustered(hist, (u32)((k >> shift) & 4095u), lane);
      }
    } else {
      for (int i = tid; i < n; i += NT) {
        u64 k = keys[i];
        if ((k & hiMask) == (prefix & hiMask))
          atomicAdd(&hist[(u32)((k >> shift) & 4095u)], 1u);
      }
    }
    __syncthreads();
    suffix_pick(hist, waveTot, waveSufExcl, prefixSh, rankSh, binCntSh, prefix, rank, shift, tid, lane, wv);
    __syncthreads();
    prefix = *prefixSh; rank = *rankSh;
    __syncthreads();
  }
  return prefix;
}

// ballot-compaction gather of keys >= K into dst
__device__ __forceinline__ void gather_ge(const u64* keys, int n, u64 K, u64* dst, u32* cnt,
                                          int tid, int lane, u32 bound) {
  for (int i = tid; i < n; i += NT) {
    u64 k = keys[i];
    bool sel = (k >= K);
    u64 mask = __ballot(sel);
    if (mask) {
      int leader = __ffsll((unsigned long long)mask) - 1;
      u32 basep = 0;
      if (lane == leader) basep = atomicAdd(cnt, (u32)__popcll((unsigned long long)mask));
      basep = __shfl((int)basep, leader);
      if (sel) {
        u32 pos = basep + (u32)__popcll((unsigned long long)(mask & ((1ull << lane) - 1ull)));
        if (pos < bound) dst[pos] = k;
      }
    }
  }
}

__device__ __forceinline__ void decode_into(DecodeArrays* d, int rk, u64 my, int b,
                                            const float* bb0, const float* bb1, const float* bb2) {
  int label = (int)(u32)(my & 0xFFFFull);
  int idx = 0xFFFF - (int)(u32)((my >> 16) & 0xFFFFull);
  float logit = unokey32((u32)(my >> 32));
  float sc = 1.0f / (1.0f + expf(-logit));

  int w, str, off, hwl; const float* bb;
  if (idx < 6400)      { w = 80; str = 8;  off = 0;    hwl = 6400; bb = bb0; }
  else if (idx < 8000) { w = 40; str = 16; off = 6400; hwl = 1600; bb = bb1; }
  else                 { w = 20; str = 32; off = 8000; hwl = 400;  bb = bb2; }
  int p = idx - off;
  int y = p / w;
  int x = p - y * w;
  float fs = (float)str;
  float px = ((float)x + 0.5f) * fs;
  float py = ((float)y + 0.5f) * fs;
  const float* bp = bb + (size_t)b * 4 * hwl + p;
  float t0 = bp[0] * fs;
  float t1 = bp[hwl] * fs;
  float t2 = bp[2 * hwl] * fs;
  float t3 = bp[3 * hwl] * fs;
  float x1 = px - t0, y1 = py - t1, x2 = px + t2, y2 = py + t3;
  float lo = (float)label * 4096.0f;
  float ox1 = x1 + lo, oy1 = y1 + lo, ox2 = x2 + lo, oy2 = y2 + lo;
  float area = (ox2 - ox1) * (oy2 - oy1);  // ref computes area from OFFSET boxes

  d->xo1[rk] = ox1; d->yo1[rk] = oy1; d->xo2[rk] = ox2; d->yo2[rk] = oy2; d->ar[rk] = area;
  d->rx1[rk] = x1;  d->ry1[rk] = y1;  d->rx2[rk] = x2;  d->ry2[rk] = y2;  d->sc[rk] = sc;
  d->lab[rk] = label;
  d->val[rk] = (sc > 0.25f) ? 1 : 0;
}

// serial greedy NMS (fallback only; call under tid<64). Returns kept count.
__device__ __forceinline__ int nms_pass(const DecodeArrays* d, int bound, int lane, int* outIdx) {
  float ax1 = 0, ay1 = 0, ax2 = 0, ay2 = 0, aar = 0; int aon = 0;
  float bx1 = 0, by1 = 0, bx2 = 0, by2 = 0, bar = 0; int bon = 0;
  int kept = 0;
  for (int i = 0; i < bound; ++i) {
    if (kept >= 100) break;
    float cx1 = d->xo1[i], cy1 = d->yo1[i], cx2 = d->xo2[i], cy2 = d->yo2[i], car = d->ar[i];
    bool sup = false;
    if (aon) {
      float ltx = fmaxf(ax1, cx1), lty = fmaxf(ay1, cy1);
      float rbx = fminf(ax2, cx2), rby = fminf(ay2, cy2);
      float wd = fmaxf(rbx - ltx, 0.0f), ht = fmaxf(rby - lty, 0.0f);
      float inter = wd * ht;
      sup = sup || ((inter / (aar + car - inter + 1e-7f)) > 0.65f);
    }
    if (bon) {
      float ltx = fmaxf(bx1, cx1), lty = fmaxf(by1, cy1);
      float rbx = fminf(bx2, cx2), rby = fminf(by2, cy2);
      float wd = fmaxf(rbx - ltx, 0.0f), ht = fmaxf(rby - lty, 0.0f);
      float inter = wd * ht;
      sup = sup || ((inter / (bar + car - inter + 1e-7f)) > 0.65f);
    }
    bool anysup = __any(sup);
    if (d->val[i] != 0 && !anysup) {
      if (kept < 64) {
        if (lane == kept) { ax1 = cx1; ay1 = cy1; ax2 = cx2; ay2 = cy2; aar = car; aon = 1; }
      } else {
        if (lane == kept - 64) { bx1 = cx1; by1 = cy1; bx2 = cx2; by2 = cy2; bar = car; bon = 1; }
      }
      if (lane == 0) outIdx[kept] = i;
      ++kept;
    }
  }
  return kept;
}

__global__ __launch_bounds__(1024) void knms(const u64* __restrict__ part, int nchunk,
                                             const float* __restrict__ bb0,
                                             const float* __restrict__ bb1,
                                             const float* __restrict__ bb2,
                                             float* __restrict__ out) {
  __shared__ union ShU {
    u64 fk[NANC];      // dead after gather (fast path); re-staged in fallback
    DecodeArrays d;    // aliases fk
  } sh;
  __shared__ u32 hist[4096];
  __shared__ u32 waveTot[16];
  __shared__ u32 waveSufExcl[16];
  __shared__ u64 prefixSh;
  __shared__ u32 rankSh, binCntSh;
  __shared__ u32 gcnt, aCnt, cCnt;
  __shared__ __align__(16) u64 cand[NCAND];    // crossing-bin buffer / fallback gather
  __shared__ __align__(16) u64 candA[NBATCH];  // fast-path final 128
  __shared__ __align__(16) u32 cm[NBATCH * 4]; // 128x128 suppression bitmatrix (rows)
  __shared__ u64 VwSh[2];                      // valid bitmask (sorted order)
  __shared__ int outIdx[128];
  __shared__ int keptSh;

  int b = blockIdx.x;
  int tid = threadIdx.x;
  int lane = tid & 63;
  int wv = tid >> 6;

  const u64x2* psrc = (const u64x2*)(part + (size_t)b * NANC);
  const size_t PL2 = (size_t)BB * NANC / 2;  // plane stride in u64x2

  // ---- fused: reduce partials -> final keys -> LDS, building pass-3 histogram in the same sweep ----
  for (int i = tid; i < 4096; i += NT) hist[i] = 0;
  if (tid == 0) { aCnt = 0; cCnt = 0; }
  __syncthreads();
  {
    u64x2* fdst = (u64x2*)sh.fk;
    for (int i = tid; i < NANC / 2; i += NT) {
      u64x2 k = reduce_pair(psrc, PL2, nchunk, i);
      fdst[i] = k;
      hist_add12(hist, (u32)(k[0] >> 52), lane);
      hist_add12(hist, (u32)(k[1] >> 52), lane);
    }
  }
  __syncthreads();

  // ---- pass-3 pick (target 128) ----
  suffix_pick(hist, waveTot, waveSufExcl, &prefixSh, &rankSh, &binCntSh,
              0ull, NBATCH, 52, tid, lane, wv);
  __syncthreads();
  u64 pfx3 = prefixSh; u32 r3 = rankSh; u32 l3 = binCntSh;
  u32 d3 = (u32)(pfx3 >> 52);
  __syncthreads();

  bool pathological = false;
  if (l3 == r3) {
    // crossing-bin count == residual rank -> K = pfx3 (zeros below) is already exact:
    // count(key >= pfx3) = (greater bins) + l3 = (128 - r3) + r3 = 128.
    gather_ge(sh.fk, NANC, pfx3, candA, &aCnt, tid, lane, NBATCH);
    __syncthreads();
  } else {
    // ---- compaction: digit>d3 -> candA (definite top); digit==d3 -> cand (crossing bin) ----
    for (int i = tid; i < NANC; i += NT) {
      u64 k = sh.fk[i];
      u32 dig = (u32)(k >> 52);
      bool selA = dig > d3;
      u64 mA = __ballot(selA);
      if (mA) {
        int leader = __ffsll((unsigned long long)mA) - 1;
        u32 basep = 0;
        if (lane == leader) basep = atomicAdd(&aCnt, (u32)__popcll((unsigned long long)mA));
        basep = __shfl((int)basep, leader);
        if (selA) {
          u32 pos = basep + (u32)__popcll((unsigned long long)(mA & ((1ull << lane) - 1ull)));
          if (pos < NBATCH) candA[pos] = k;
        }
      }
      bool selC = (dig == d3);
      u64 mC = __ballot(selC);
      if (mC) {
        int leader = __ffsll((unsigned long long)mC) - 1;
        u32 basep = 0;
        if (lane == leader) basep = atomicAdd(&cCnt, (u32)__popcll((unsigned long long)mC));
        basep = __shfl((int)basep, leader);
        if (selC) {
          u32 pos = basep + (u32)__popcll((unsigned long long)(mC & ((1ull << lane) - 1ull)));
          if (pos < NCAND) cand[pos] = k;
        }
      }
    }
    __syncthreads();

    u32 cnt3 = cCnt;  // uniform
    if (cnt3 <= NCAND) {
      // ---- refine within crossing bin, early-exit when bin count == residual rank ----
      u64 pfx = pfx3; u32 rk = r3;
      u64 Kf = 0; bool done = false;
      for (int pass = 2; pass >= 0 && !done; --pass) {
        int shift = 16 + pass * 12;
        for (int i = tid; i < 4096; i += NT) hist[i] = 0;
        __syncthreads();
        u64 hiMask = (~0ull) << (shift + 12);
        for (int i = tid; i < (int)cnt3; i += NT) {
          u64 k = cand[i];
          if ((k & hiMask) == (pfx & hiMask))
            atomicAdd(&hist[(u32)((k >> shift) & 4095u)], 1u);
        }
        __syncthreads();
        suffix_pick(hist, waveTot, waveSufExcl, &prefixSh, &rankSh, &binCntSh,
                    pfx, rk, shift, tid, lane, wv);
        __syncthreads();
        pfx = prefixSh; rk = rankSh;
        u32 lc = binCntSh;
        __syncthreads();
        if (lc == rk || pass == 0) { done = true; Kf = pfx; }
      }
      // append crossing keys >= Kf (exactly r3) -> candA fills to 128
      gather_ge(cand, (int)cnt3, Kf, candA, &aCnt, tid, lane, NBATCH);
      __syncthreads();
    } else {
      pathological = true;
    }
  }

  if (pathological) {
    // crossing bin overflow: full 4-pass select + gather (always correct)
    if (tid == 0) aCnt = 0;
    __syncthreads();
    u64 K2 = radix_select(sh.fk, NANC, NBATCH, hist, waveTot, waveSufExcl,
                          &prefixSh, &rankSh, &binCntSh, tid, lane, wv);
    gather_ge(sh.fk, NANC, K2, candA, &aCnt, tid, lane, NBATCH);
    __syncthreads();
  }

  // ---- rank-sort 128 + decode (scatter by rank); zero bitmatrix in parallel ----
  if (tid < NBATCH) {
    u64 my = candA[tid];
    int rk = 0;
    const u64x2* cav = (const u64x2*)candA;
    #pragma unroll
    for (int j2 = 0; j2 < NBATCH / 2; ++j2) {
      u64x2 p = cav[j2];
      rk += (p[0] > my) ? 1 : 0;
      rk += (p[1] > my) ? 1 : 0;
    }
    decode_into(&sh.d, rk, my, b, bb0, bb1, bb2);
  }
  if (tid < NBATCH * 4) cm[tid] = 0;
  __syncthreads();

  // ---- valid bitmask (sorted order) ----
  if (tid < NBATCH) {
    u64 bal = __ballot(sh.d.val[tid] != 0);
    if (lane == 0) VwSh[tid >> 6] = bal;
  }

  // ---- build 128x128 suppression matrix: thread t -> row c = t&127, j-group g = t>>7 ----
  {
    int c = tid & 127;
    int g = tid >> 7;  // 0..7, wave-uniform
    float cx1 = sh.d.xo1[c], cy1 = sh.d.yo1[c], cx2 = sh.d.xo2[c], cy2 = sh.d.yo2[c], car = sh.d.ar[c];
    u32 bits = 0;
    int j0 = g * 16;
    for (int jj = 0; jj < 16; ++jj) {
      int j = j0 + jj;
      float ltx = fmaxf(sh.d.xo1[j], cx1), lty = fmaxf(sh.d.yo1[j], cy1);
      float rbx = fminf(sh.d.xo2[j], cx2), rby = fminf(sh.d.yo2[j], cy2);
      float wd = fmaxf(rbx - ltx, 0.0f), ht = fmaxf(rby - lty, 0.0f);
      float inter = wd * ht;
      bool sup = (inter / (sh.d.ar[j] + car - inter + 1e-7f)) > 0.65f;
      bits |= sup ? (1u << jj) : 0u;
    }
    atomicOr(&cm[c * 4 + (g >> 1)], bits << ((g & 1) * 16));
  }
  __syncthreads();

  // ---- greedy scan: live-mask + ffs; iterate kept candidates only ----
  if (tid == 0) {
    u32 L0 = (u32)VwSh[0], L1 = (u32)(VwSh[0] >> 32);
    u32 L2 = (u32)VwSh[1], L3 = (u32)(VwSh[1] >> 32);
    int kept = 0;
    while (kept < 100) {
      int i;
      if (L0)      i = __ffs(L0) - 1;
      else if (L1) i = 31 + __ffs(L1);
      else if (L2) i = 63 + __ffs(L2);
      else if (L3) i = 95 + __ffs(L3);
      else break;
      outIdx[kept++] = i;
      const u32* c4 = &cm[i * 4];
      L0 &= ~c4[0]; L1 &= ~c4[1]; L2 &= ~c4[2]; L3 &= ~c4[3];
      if (i < 32)      L0 &= ~(1u << i);
      else if (i < 64) L1 &= ~(1u << (i - 32));
      else if (i < 96) L2 &= ~(1u << (i - 64));
      else             L3 &= ~(1u << (i - 96));
    }
    keptSh = kept;
  }
  __syncthreads();

  // ---- RARE FALLBACK: <100 kept within 128 -> exact top-1000 restart (serial NMS) ----
  if (keptSh < 100) {
    {  // re-stage with inline reduce (sh.d overwrote fk)
      u64x2* fdst = (u64x2*)sh.fk;
      for (int i = tid; i < NANC / 2; i += NT)
        fdst[i] = reduce_pair(psrc, PL2, nchunk, i);
    }
    __syncthreads();
    u64 K = radix_select(sh.fk, NANC, NSEL, hist, waveTot, waveSufExcl,
                         &prefixSh, &rankSh, &binCntSh, tid, lane, wv);
    if (tid == 0) gcnt = 0;
    __syncthreads();
    gather_ge(sh.fk, NANC, K, cand, &gcnt, tid, lane, NSEL);
    __syncthreads();
    if (tid < NSEL) {
      u64 my = cand[tid];
      int rk = 0;
      const u64x2* cbv = (const u64x2*)cand;
      for (int j2 = 0; j2 < NSEL / 2; ++j2) {
        u64x2 p = cbv[j2];
        rk += (p[0] > my) ? 1 : 0;
        rk += (p[1] > my) ? 1 : 0;
      }
      decode_into(&sh.d, rk, my, b, bb0, bb1, bb2);
    }
    __syncthreads();
    if (tid < 64) {
      int kept = nms_pass(&sh.d, NSEL, lane, outIdx);
      if (lane == 0) keptSh = kept;
    }
    __syncthreads();
  }

  // ---- write outputs: num_dets[8] | boxes[8,100,4] | scores[8,100] | labels[8,100] ----
  int kept = keptSh;
  float* o_nd = out;
  float* o_box = out + BB;
  float* o_sc = out + BB + BB * 100 * 4;
  float* o_lb = out + BB + BB * 100 * 4 + BB * 100;
  if (tid == 0) o_nd[b] = (float)kept;
  if (tid < 100) {
    int s = tid;
    float v0 = 0, v1 = 0, v2 = 0, v3 = 0, sv = 0, lv = -1.0f;
    if (s < kept) {
      int i = outIdx[s];
      v0 = sh.d.rx1[i]; v1 = sh.d.ry1[i]; v2 = sh.d.rx2[i]; v3 = sh.d.ry2[i];
      sv = sh.d.sc[i]; lv = (float)sh.d.lab[i];
    }
    float* bo = o_box + ((size_t)b * 100 + s) * 4;
    bo[0] = v0; bo[1] = v1; bo[2] = v2; bo[3] = v3;
    o_sc[b * 100 + s] = sv;
    o_lb[b * 100 + s] = lv;
  }
}

extern "C" void kernel_launch(void* const* d_in, const int* in_sizes, int n_in,
                              void* d_out, int out_size, void* d_ws, size_t ws_size,
                              hipStream_t stream) {
  const float* cls0 = (const float*)d_in[0];  // [8,1203,80,80]
  const float* bb0  = (const float*)d_in[1];  // [8,4,80,80]
  const float* cls1 = (const float*)d_in[2];  // [8,1203,40,40]
  const float* bb1  = (const float*)d_in[3];  // [8,4,40,40]
  const float* cls2 = (const float*)d_in[4];  // [8,1203,20,20]
  const float* bb2  = (const float*)d_in[5];  // [8,4,20,20]

  size_t planeB = (size_t)BB * NANC * sizeof(u64);
  u64* part = (u64*)d_ws;
  int nchunk = (int)(ws_size / planeB);
  if (nchunk < 1) nchunk = 1;
  if (nchunk > NCHUNK_MAX) nchunk = NCHUNK_MAX;
  int chunkSz = (CC_TOT + nchunk - 1) / nchunk;
  nchunk = (CC_TOT + chunkSz - 1) / chunkSz;  // no empty chunks

  kmax<<<dim3(10 * nchunk * BB), dim3(256), 0, stream>>>(cls0, cls1, cls2, part, chunkSz, nchunk);
  knms<<<dim3(BB), dim3(NT), 0, stream>>>(part, nchunk, bb0, bb1, bb2, (float*)d_out);
}

// Round 11
// 119.773 us; speedup vs baseline: 1.1075x; 1.1075x over previous
//
#include <hip/hip_runtime.h>
#include <math.h>

#pragma clang fp contract(off)

typedef unsigned long long u64;
typedef unsigned int u32;
typedef float f4 __attribute__((ext_vector_type(4)));
typedef unsigned long long u64x2 __attribute__((ext_vector_type(2)));

#define BB 8
#define CC_TOT 1203
#define NANC 8400
#define NSEG 8
#define SEGN 1050
#define NSEL 1000
#define NCAND 1024
#define NT 1024
#define NBATCH 128
#define NCHUNK_MAX 16

// order-preserving transform: float -> u32 with unsigned order == float order
__device__ __forceinline__ u32 okey32(float v) {
  u32 b = __float_as_uint(v);
  return (b & 0x80000000u) ? ~b : (b | 0x80000000u);
}

__device__ __forceinline__ float unokey32(u32 ok) {
  u32 fb = (ok & 0x80000000u) ? (ok & 0x7FFFFFFFu) : ~ok;
  return __uint_as_float(fb);
}

// ---------------- kernel 1 (unchanged — ~94% of achievable HBM BW) ----------------
__global__ __launch_bounds__(256) void kmax(const float* __restrict__ cls0,
                                            const float* __restrict__ cls1,
                                            const float* __restrict__ cls2,
                                            u64* __restrict__ part,
                                            int chunkSz, int nchunk) {
  int bx = blockIdx.x;
  int per = nchunk * BB;
  int tg = bx / per;
  int rem = bx - tg * per;
  int chunk = rem >> 3;
  int b = rem & 7;
  const float* cls; int hw4, aoff, col0;
  if (tg < 7)      { cls = cls0; hw4 = 1600; aoff = 0;    col0 = tg << 8; }
  else if (tg < 9) { cls = cls1; hw4 = 400;  aoff = 6400; col0 = (tg - 7) << 8; }
  else             { cls = cls2; hw4 = 100;  aoff = 8000; col0 = 0; }
  int col = col0 + (int)threadIdx.x;
  if (col >= hw4) return;
  int c0 = chunk * chunkSz;
  int c1 = c0 + chunkSz; if (c1 > CC_TOT) c1 = CC_TOT;

  const f4* base = (const f4*)cls + (size_t)b * CC_TOT * hw4 + col;
  f4 m = (f4){-3.4e38f, -3.4e38f, -3.4e38f, -3.4e38f};
  int ix0 = c0, ix1 = c0, ix2 = c0, ix3 = c0;

#define UPD(v, c)                                   \
  do {                                              \
    if ((v)[0] > m[0]) { m[0] = (v)[0]; ix0 = (c); } \
    if ((v)[1] > m[1]) { m[1] = (v)[1]; ix1 = (c); } \
    if ((v)[2] > m[2]) { m[2] = (v)[2]; ix2 = (c); } \
    if ((v)[3] > m[3]) { m[3] = (v)[3]; ix3 = (c); } \
  } while (0)

  int c = c0;
  for (; c + 8 <= c1; c += 8) {
    const f4* p = base + (size_t)c * hw4;
    f4 v0 = p[0];
    f4 v1 = p[(size_t)1 * hw4];
    f4 v2 = p[(size_t)2 * hw4];
    f4 v3 = p[(size_t)3 * hw4];
    f4 v4 = p[(size_t)4 * hw4];
    f4 v5 = p[(size_t)5 * hw4];
    f4 v6 = p[(size_t)6 * hw4];
    f4 v7 = p[(size_t)7 * hw4];
    UPD(v0, c + 0); UPD(v1, c + 1); UPD(v2, c + 2); UPD(v3, c + 3);
    UPD(v4, c + 4); UPD(v5, c + 5); UPD(v6, c + 6); UPD(v7, c + 7);
  }
  for (; c < c1; ++c) {
    f4 v = base[(size_t)c * hw4];
    UPD(v, c);
  }
#undef UPD

  u64* dst = part + ((size_t)chunk * BB + b) * NANC + aoff + (size_t)col * 4;
  u64x2 s01 = { ((u64)okey32(m[0]) << 32) | (u64)(u32)~(u32)ix0,
                ((u64)okey32(m[1]) << 32) | (u64)(u32)~(u32)ix1 };
  u64x2 s23 = { ((u64)okey32(m[2]) << 32) | (u64)(u32)~(u32)ix2,
                ((u64)okey32(m[3]) << 32) | (u64)(u32)~(u32)ix3 };
  *((u64x2*)dst)     = s01;
  *((u64x2*)dst + 1) = s23;
}

// ---------------- shared select machinery ----------------
struct DecodeArrays {
  float xo1[NCAND], yo1[NCAND], xo2[NCAND], yo2[NCAND], ar[NCAND];
  float rx1[NCAND], ry1[NCAND], rx2[NCAND], ry2[NCAND], sc[NCAND];
  int lab[NCAND], val[NCAND];
};

// ballot-clustered histogram add, 13-bit digit with sentinel (digit>=4096 -> no add)
__device__ __forceinline__ void hist_addc(u32* hist, u32 digit, int lane) {
  u64 peers = ~0ull;
  for (int bit = 0; bit < 13; ++bit) {
    u64 bal = __ballot((digit >> bit) & 1u);
    peers &= ((digit >> bit) & 1u) ? bal : ~bal;
  }
  int leader = __ffsll((unsigned long long)peers) - 1;
  if (digit < 4096u && lane == leader)
    atomicAdd(&hist[digit], (u32)__popcll((unsigned long long)peers));
}

// suffix-scan over 4096 bins + pick crossing digit + crossing-bin count.
// ALL NT threads must call (has barriers).
__device__ __forceinline__ void suffix_pick(u32* hist, u32* waveTot, u32* waveSufExcl,
                                            u64* prefixSh, u32* rankSh, u32* binCntSh,
                                            u64 prefix, u32 rank, int shift,
                                            int tid, int lane, int wv) {
  u32 l0 = hist[4 * tid], l1 = hist[4 * tid + 1], l2 = hist[4 * tid + 2], l3 = hist[4 * tid + 3];
  u32 psum = l0 + l1 + l2 + l3;
  u32 x = psum;
  for (int s = 1; s < 64; s <<= 1) { u32 v = __shfl_down(x, s); if (lane + s < 64) x += v; }
  if (lane == 0) waveTot[wv] = x;
  __syncthreads();
  if (tid < 16) {
    u32 y = waveTot[tid]; u32 z = y;
    for (int s = 1; s < 16; s <<= 1) { u32 v = __shfl_down(z, s); if (tid + s < 16) z += v; }
    waveSufExcl[tid] = z - y;
  }
  __syncthreads();
  u32 S = x + waveSufExcl[wv];
  u32 G3 = S - psum; u32 G2 = G3 + l3; u32 G1 = G2 + l2; u32 G0 = G1 + l1;
  u32 r = rank;
  if      (G3 < r && G3 + l3 >= r) { *prefixSh = prefix | ((u64)(4u * tid + 3) << shift); *rankSh = r - G3; *binCntSh = l3; }
  else if (G2 < r && G2 + l2 >= r) { *prefixSh = prefix | ((u64)(4u * tid + 2) << shift); *rankSh = r - G2; *binCntSh = l2; }
  else if (G1 < r && G1 + l1 >= r) { *prefixSh = prefix | ((u64)(4u * tid + 1) << shift); *rankSh = r - G1; *binCntSh = l1; }
  else if (G0 < r && G0 + l0 >= r) { *prefixSh = prefix | ((u64)(4u * tid + 0) << shift); *rankSh = r - G0; *binCntSh = l0; }
}

// exact rank-'target' threshold; expects hist prebuilt with pass-3 (bits 52..63) counts.
// Early-exits when crossing-bin count == residual rank (then prefix with zero low bits is
// exact: count(key>=prefix) = (target - rank) + binCnt = target). Bit-exact in all cases.
__device__ __forceinline__ u64 select_after_hist(const u64* keys, int n, u32 target,
                                                 u32* hist, u32* waveTot, u32* waveSufExcl,
                                                 u64* prefixSh, u32* rankSh, u32* binCntSh,
                                                 int tid, int lane, int wv) {
  suffix_pick(hist, waveTot, waveSufExcl, prefixSh, rankSh, binCntSh,
              0ull, target, 52, tid, lane, wv);
  __syncthreads();
  u64 pfx = *prefixSh; u32 rk = *rankSh; u32 lc = *binCntSh;
  __syncthreads();
  if (lc == rk) return pfx;
  for (int pass = 2; pass >= 0; --pass) {
    int shift = 16 + pass * 12;
    for (int i = tid; i < 4096; i += NT) hist[i] = 0;
    __syncthreads();
    u64 hiMask = (~0ull) << (shift + 12);
    for (int i = tid; i < n; i += NT) {
      u64 k = keys[i];
      if ((k & hiMask) == (pfx & hiMask))
        atomicAdd(&hist[(u32)((k >> shift) & 4095u)], 1u);
    }
    __syncthreads();
    suffix_pick(hist, waveTot, waveSufExcl, prefixSh, rankSh, binCntSh,
                pfx, rk, shift, tid, lane, wv);
    __syncthreads();
    pfx = *prefixSh; rk = *rankSh; lc = *binCntSh;
    __syncthreads();
    if (lc == rk) break;
  }
  return pfx;
}

// ballot-compaction gather of keys >= K into dst (LDS or global)
__device__ __forceinline__ void gather_ge(const u64* keys, int n, u64 K, u64* dst, u32* cnt,
                                          int tid, int lane, u32 bound) {
  for (int i = tid; i < n; i += NT) {
    u64 k = keys[i];
    bool sel = (k >= K);
    u64 mask = __ballot(sel);
    if (mask) {
      int leader = __ffsll((unsigned long long)mask) - 1;
      u32 basep = 0;
      if (lane == leader) basep = atomicAdd(cnt, (u32)__popcll((unsigned long long)mask));
      basep = __shfl((int)basep, leader);
      if (sel) {
        u32 pos = basep + (u32)__popcll((unsigned long long)(mask & ((1ull << lane) - 1ull)));
        if (pos < bound) dst[pos] = k;
      }
    }
  }
}

// ---------------- kernel 1b: per-(image, segment) reduce + exact segment top-128 ----------------
// Global top-128 of an image is contained in the union of its 8 segment top-128s.
__global__ __launch_bounds__(1024) void kseg(const u64* __restrict__ part, int nchunk,
                                             u64* __restrict__ candSeg) {
  __shared__ __align__(16) u64 keys[SEGN];
  __shared__ u32 hist[4096];
  __shared__ u32 waveTot[16], waveSufExcl[16];
  __shared__ u64 prefixSh;
  __shared__ u32 rankSh, binCntSh, cnt;

  int seg = blockIdx.x >> 3;
  int b = blockIdx.x & 7;
  int tid = threadIdx.x, lane = tid & 63, wv = tid >> 6;
  int a0 = seg * SEGN;

  const u64x2* psrc = (const u64x2*)part + ((size_t)b * NANC + a0) / 2;
  const size_t PL2 = (size_t)BB * NANC / 2;

  for (int i = tid; i < 4096; i += NT) hist[i] = 0;
  if (tid == 0) cnt = 0;
  __syncthreads();

  // reduce 16 partial planes (4-batched MLP) -> keys in LDS; fuse pass-3 histogram
  {
    u32 d0 = 4096u, d1 = 4096u;  // sentinel for inactive threads
    if (tid < SEGN / 2) {
      u64x2 m = psrc[tid];
      int ch = 1;
      for (; ch + 4 <= nchunk; ch += 4) {
        u64x2 v0 = psrc[(size_t)(ch + 0) * PL2 + tid];
        u64x2 v1 = psrc[(size_t)(ch + 1) * PL2 + tid];
        u64x2 v2 = psrc[(size_t)(ch + 2) * PL2 + tid];
        u64x2 v3 = psrc[(size_t)(ch + 3) * PL2 + tid];
        u64 a01 = (v0[0] > v1[0]) ? v0[0] : v1[0];
        u64 a23 = (v2[0] > v3[0]) ? v2[0] : v3[0];
        u64 aa = (a01 > a23) ? a01 : a23;
        if (aa > m[0]) m[0] = aa;
        u64 b01 = (v0[1] > v1[1]) ? v0[1] : v1[1];
        u64 b23 = (v2[1] > v3[1]) ? v2[1] : v3[1];
        u64 bb2_ = (b01 > b23) ? b01 : b23;
        if (bb2_ > m[1]) m[1] = bb2_;
      }
      for (; ch < nchunk; ++ch) {
        u64x2 v = psrc[(size_t)ch * PL2 + tid];
        if (v[0] > m[0]) m[0] = v[0];
        if (v[1] > m[1]) m[1] = v[1];
      }
      u32 aA = (u32)(a0 + 2 * tid), aB = aA + 1;
      u64 k0 = (m[0] & 0xFFFFFFFF00000000ull) | ((u64)(0xFFFFu - aA) << 16) | (u64)(~(u32)m[0] & 0xFFFFu);
      u64 k1 = (m[1] & 0xFFFFFFFF00000000ull) | ((u64)(0xFFFFu - aB) << 16) | (u64)(~(u32)m[1] & 0xFFFFu);
      keys[2 * tid] = k0;
      keys[2 * tid + 1] = k1;
      d0 = (u32)(k0 >> 52);
      d1 = (u32)(k1 >> 52);
    }
    hist_addc(hist, d0, lane);
    hist_addc(hist, d1, lane);
  }
  __syncthreads();

  u64 K = select_after_hist(keys, SEGN, NBATCH, hist, waveTot, waveSufExcl,
                            &prefixSh, &rankSh, &binCntSh, tid, lane, wv);
  gather_ge(keys, SEGN, K, candSeg + ((size_t)b * NSEG + seg) * NBATCH, &cnt,
            tid, lane, NBATCH);
}

// ---------------- decode / NMS helpers ----------------
__device__ __forceinline__ void decode_into(DecodeArrays* d, int rk, u64 my, int b,
                                            const float* bb0, const float* bb1, const float* bb2) {
  int label = (int)(u32)(my & 0xFFFFull);
  int idx = 0xFFFF - (int)(u32)((my >> 16) & 0xFFFFull);
  float logit = unokey32((u32)(my >> 32));
  float sc = 1.0f / (1.0f + expf(-logit));

  int w, str, off, hwl; const float* bb;
  if (idx < 6400)      { w = 80; str = 8;  off = 0;    hwl = 6400; bb = bb0; }
  else if (idx < 8000) { w = 40; str = 16; off = 6400; hwl = 1600; bb = bb1; }
  else                 { w = 20; str = 32; off = 8000; hwl = 400;  bb = bb2; }
  int p = idx - off;
  int y = p / w;
  int x = p - y * w;
  float fs = (float)str;
  float px = ((float)x + 0.5f) * fs;
  float py = ((float)y + 0.5f) * fs;
  const float* bp = bb + (size_t)b * 4 * hwl + p;
  float t0 = bp[0] * fs;
  float t1 = bp[hwl] * fs;
  float t2 = bp[2 * hwl] * fs;
  float t3 = bp[3 * hwl] * fs;
  float x1 = px - t0, y1 = py - t1, x2 = px + t2, y2 = py + t3;
  float lo = (float)label * 4096.0f;
  float ox1 = x1 + lo, oy1 = y1 + lo, ox2 = x2 + lo, oy2 = y2 + lo;
  float area = (ox2 - ox1) * (oy2 - oy1);  // ref computes area from OFFSET boxes

  d->xo1[rk] = ox1; d->yo1[rk] = oy1; d->xo2[rk] = ox2; d->yo2[rk] = oy2; d->ar[rk] = area;
  d->rx1[rk] = x1;  d->ry1[rk] = y1;  d->rx2[rk] = x2;  d->ry2[rk] = y2;  d->sc[rk] = sc;
  d->lab[rk] = label;
  d->val[rk] = (sc > 0.25f) ? 1 : 0;
}

// serial greedy NMS (fallback only; call under tid<64). Returns kept count.
__device__ __forceinline__ int nms_pass(const DecodeArrays* d, int bound, int lane, int* outIdx) {
  float ax1 = 0, ay1 = 0, ax2 = 0, ay2 = 0, aar = 0; int aon = 0;
  float bx1 = 0, by1 = 0, bx2 = 0, by2 = 0, bar = 0; int bon = 0;
  int kept = 0;
  for (int i = 0; i < bound; ++i) {
    if (kept >= 100) break;
    float cx1 = d->xo1[i], cy1 = d->yo1[i], cx2 = d->xo2[i], cy2 = d->yo2[i], car = d->ar[i];
    bool sup = false;
    if (aon) {
      float ltx = fmaxf(ax1, cx1), lty = fmaxf(ay1, cy1);
      float rbx = fminf(ax2, cx2), rby = fminf(ay2, cy2);
      float wd = fmaxf(rbx - ltx, 0.0f), ht = fmaxf(rby - lty, 0.0f);
      float inter = wd * ht;
      sup = sup || ((inter / (aar + car - inter + 1e-7f)) > 0.65f);
    }
    if (bon) {
      float ltx = fmaxf(bx1, cx1), lty = fmaxf(by1, cy1);
      float rbx = fminf(bx2, cx2), rby = fminf(by2, cy2);
      float wd = fmaxf(rbx - ltx, 0.0f), ht = fmaxf(rby - lty, 0.0f);
      float inter = wd * ht;
      sup = sup || ((inter / (bar + car - inter + 1e-7f)) > 0.65f);
    }
    bool anysup = __any(sup);
    if (d->val[i] != 0 && !anysup) {
      if (kept < 64) {
        if (lane == kept) { ax1 = cx1; ay1 = cy1; ax2 = cx2; ay2 = cy2; aar = car; aon = 1; }
      } else {
        if (lane == kept - 64) { bx1 = cx1; by1 = cy1; bx2 = cx2; by2 = cy2; bar = car; bon = 1; }
      }
      if (lane == 0) outIdx[kept] = i;
      ++kept;
    }
  }
  return kept;
}

// ---------------- kernel 2: merge 1024 candidates -> top-128 -> matrix NMS -> output ----------------
__global__ __launch_bounds__(1024) void kmerge(const u64* __restrict__ part, int nchunk,
                                               const u64* __restrict__ candSeg,
                                               const float* __restrict__ bb0,
                                               const float* __restrict__ bb1,
                                               const float* __restrict__ bb2,
                                               float* __restrict__ out) {
  __shared__ union ShU {
    u64 fk[NANC];      // fallback restage only
    DecodeArrays d;    // aliases fk
  } sh;
  __shared__ u32 hist[4096];
  __shared__ u32 waveTot[16], waveSufExcl[16];
  __shared__ u64 prefixSh;
  __shared__ u32 rankSh, binCntSh;
  __shared__ u32 gcnt, aCnt;
  __shared__ __align__(16) u64 cand[NCAND];
  __shared__ __align__(16) u64 candA[NBATCH];
  __shared__ __align__(16) u32 cm[NBATCH * 4];
  __shared__ u64 VwSh[2];
  __shared__ int outIdx[128];
  __shared__ int keptSh;

  int b = blockIdx.x;
  int tid = threadIdx.x;
  int lane = tid & 63;
  int wv = tid >> 6;

  // ---- load 1024 merged candidates; fuse pass-3 histogram; zero bitmatrix ----
  for (int i = tid; i < 4096; i += NT) hist[i] = 0;
  if (tid == 0) { gcnt = 0; aCnt = 0; }
  __syncthreads();
  u64 myk = candSeg[(size_t)b * (NSEG * NBATCH) + tid];
  cand[tid] = myk;
  hist_addc(hist, (u32)(myk >> 52), lane);
  if (tid < NBATCH * 4) cm[tid] = 0;
  __syncthreads();

  // ---- exact top-128 among the 1024 (== exact global top-128) ----
  u64 K = select_after_hist(cand, NCAND, NBATCH, hist, waveTot, waveSufExcl,
                            &prefixSh, &rankSh, &binCntSh, tid, lane, wv);
  gather_ge(cand, NCAND, K, candA, &aCnt, tid, lane, NBATCH);
  __syncthreads();

  // ---- rank-sort 128 (2 waves) + decode by rank ----
  if (tid < NBATCH) {
    u64 my = candA[tid];
    int rk = 0;
    const u64x2* cav = (const u64x2*)candA;
    #pragma unroll
    for (int j2 = 0; j2 < NBATCH / 2; ++j2) {
      u64x2 p = cav[j2];
      rk += (p[0] > my) ? 1 : 0;
      rk += (p[1] > my) ? 1 : 0;
    }
    decode_into(&sh.d, rk, my, b, bb0, bb1, bb2);
  }
  __syncthreads();

  // ---- valid bitmask (sorted order) ----
  if (tid < NBATCH) {
    u64 bal = __ballot(sh.d.val[tid] != 0);
    if (lane == 0) VwSh[tid >> 6] = bal;
  }

  // ---- 128x128 suppression bitmatrix (symmetric IoU; row == column) ----
  {
    int c = tid & 127;
    int g = tid >> 7;  // wave-uniform
    float cx1 = sh.d.xo1[c], cy1 = sh.d.yo1[c], cx2 = sh.d.xo2[c], cy2 = sh.d.yo2[c], car = sh.d.ar[c];
    u32 bits = 0;
    int j0 = g * 16;
    for (int jj = 0; jj < 16; ++jj) {
      int j = j0 + jj;
      float ltx = fmaxf(sh.d.xo1[j], cx1), lty = fmaxf(sh.d.yo1[j], cy1);
      float rbx = fminf(sh.d.xo2[j], cx2), rby = fminf(sh.d.yo2[j], cy2);
      float wd = fmaxf(rbx - ltx, 0.0f), ht = fmaxf(rby - lty, 0.0f);
      float inter = wd * ht;
      bool sup = (inter / (sh.d.ar[j] + car - inter + 1e-7f)) > 0.65f;
      bits |= sup ? (1u << jj) : 0u;
    }
    atomicOr(&cm[c * 4 + (g >> 1)], bits << ((g & 1) * 16));
  }
  __syncthreads();

  // ---- greedy scan: live-mask + ffs ----
  if (tid == 0) {
    u32 L0 = (u32)VwSh[0], L1 = (u32)(VwSh[0] >> 32);
    u32 L2 = (u32)VwSh[1], L3 = (u32)(VwSh[1] >> 32);
    int kept = 0;
    while (kept < 100) {
      int i;
      if (L0)      i = __ffs(L0) - 1;
      else if (L1) i = 31 + __ffs(L1);
      else if (L2) i = 63 + __ffs(L2);
      else if (L3) i = 95 + __ffs(L3);
      else break;
      outIdx[kept++] = i;
      const u32* c4 = &cm[i * 4];
      L0 &= ~c4[0]; L1 &= ~c4[1]; L2 &= ~c4[2]; L3 &= ~c4[3];
      if (i < 32)      L0 &= ~(1u << i);
      else if (i < 64) L1 &= ~(1u << (i - 32));
      else if (i < 96) L2 &= ~(1u << (i - 64));
      else             L3 &= ~(1u << (i - 96));
    }
    keptSh = kept;
  }
  __syncthreads();

  // ---- RARE FALLBACK: <100 kept within top-128 -> exact top-1000 restart ----
  if (keptSh < 100) {
    const u64x2* psrc = (const u64x2*)(part + (size_t)b * NANC);
    const size_t PL2 = (size_t)BB * NANC / 2;
    for (int i = tid; i < 4096; i += NT) hist[i] = 0;
    __syncthreads();
    {
      u64x2* fdst = (u64x2*)sh.fk;
      for (int i = tid; i < NANC / 2; i += NT) {
        u64x2 m = psrc[i];
        for (int ch = 1; ch < nchunk; ++ch) {
          u64x2 v = psrc[(size_t)ch * PL2 + i];
          if (v[0] > m[0]) m[0] = v[0];
          if (v[1] > m[1]) m[1] = v[1];
        }
        u32 i0 = (u32)(2 * i), i1 = (u32)(2 * i + 1);
        u64x2 r;
        r[0] = (m[0] & 0xFFFFFFFF00000000ull) | ((u64)(0xFFFFu - i0) << 16) | (u64)(~(u32)m[0] & 0xFFFFu);
        r[1] = (m[1] & 0xFFFFFFFF00000000ull) | ((u64)(0xFFFFu - i1) << 16) | (u64)(~(u32)m[1] & 0xFFFFu);
        fdst[i] = r;
        hist_addc(hist, (u32)(r[0] >> 52), lane);
        hist_addc(hist, (u32)(r[1] >> 52), lane);
      }
    }
    __syncthreads();
    u64 Kf = select_after_hist(sh.fk, NANC, NSEL, hist, waveTot, waveSufExcl,
                               &prefixSh, &rankSh, &binCntSh, tid, lane, wv);
    gather_ge(sh.fk, NANC, Kf, cand, &gcnt, tid, lane, NSEL);
    __syncthreads();
    if (tid < NSEL) {
      u64 my = cand[tid];
      int rk = 0;
      const u64x2* cbv = (const u64x2*)cand;
      for (int j2 = 0; j2 < NSEL / 2; ++j2) {
        u64x2 p = cbv[j2];
        rk += (p[0] > my) ? 1 : 0;
        rk += (p[1] > my) ? 1 : 0;
      }
      decode_into(&sh.d, rk, my, b, bb0, bb1, bb2);
    }
    __syncthreads();
    if (tid < 64) {
      int kept = nms_pass(&sh.d, NSEL, lane, outIdx);
      if (lane == 0) keptSh = kept;
    }
    __syncthreads();
  }

  // ---- write outputs: num_dets[8] | boxes[8,100,4] | scores[8,100] | labels[8,100] ----
  int kept = keptSh;
  float* o_nd = out;
  float* o_box = out + BB;
  float* o_sc = out + BB + BB * 100 * 4;
  float* o_lb = out + BB + BB * 100 * 4 + BB * 100;
  if (tid == 0) o_nd[b] = (float)kept;
  if (tid < 100) {
    int s = tid;
    float v0 = 0, v1 = 0, v2 = 0, v3 = 0, sv = 0, lv = -1.0f;
    if (s < kept) {
      int i = outIdx[s];
      v0 = sh.d.rx1[i]; v1 = sh.d.ry1[i]; v2 = sh.d.rx2[i]; v3 = sh.d.ry2[i];
      sv = sh.d.sc[i]; lv = (float)sh.d.lab[i];
    }
    float* bo = o_box + ((size_t)b * 100 + s) * 4;
    bo[0] = v0; bo[1] = v1; bo[2] = v2; bo[3] = v3;
    o_sc[b * 100 + s] = sv;
    o_lb[b * 100 + s] = lv;
  }
}

extern "C" void kernel_launch(void* const* d_in, const int* in_sizes, int n_in,
                              void* d_out, int out_size, void* d_ws, size_t ws_size,
                              hipStream_t stream) {
  const float* cls0 = (const float*)d_in[0];  // [8,1203,80,80]
  const float* bb0  = (const float*)d_in[1];  // [8,4,80,80]
  const float* cls1 = (const float*)d_in[2];  // [8,1203,40,40]
  const float* bb1  = (const float*)d_in[3];  // [8,4,40,40]
  const float* cls2 = (const float*)d_in[4];  // [8,1203,20,20]
  const float* bb2  = (const float*)d_in[5];  // [8,4,20,20]

  size_t planeB = (size_t)BB * NANC * sizeof(u64);
  size_t candB = (size_t)BB * NSEG * NBATCH * sizeof(u64);  // 64 KB
  u64* part = (u64*)d_ws;
  int nchunk = 1;
  if (ws_size > candB + planeB) {
    nchunk = (int)((ws_size - candB) / planeB);
    if (nchunk > NCHUNK_MAX) nchunk = NCHUNK_MAX;
    if (nchunk < 1) nchunk = 1;
  }
  int chunkSz = (CC_TOT + nchunk - 1) / nchunk;
  nchunk = (CC_TOT + chunkSz - 1) / chunkSz;  // no empty chunks
  u64* candSeg = part + (size_t)nchunk * BB * NANC;

  kmax<<<dim3(10 * nchunk * BB), dim3(256), 0, stream>>>(cls0, cls1, cls2, part, chunkSz, nchunk);
  kseg<<<dim3(NSEG * BB), dim3(NT), 0, stream>>>(part, nchunk, candSeg);
  kmerge<<<dim3(BB), dim3(NT), 0, stream>>>(part, nchunk, candSeg, bb0, bb1, bb2, (float*)d_out);
}